// Round 1
// baseline (2818.586 us; speedup 1.0000x reference)
//
#include <hip/hip_runtime.h>

#define D 128

// ---------------------------------------------------------------------------
// Kernel 1: edge-parallel scatter  agg[dst] += w * h[src]
// 32 lanes per edge, float4 per lane (32*4 = 128 cols). Two edges per wave.
// Coalesced 512B gather per edge; 4 fp32 atomics per lane.
// ---------------------------------------------------------------------------
__global__ __launch_bounds__(256) void gcn_scatter(
    const float* __restrict__ h,
    const int* __restrict__ esrc,
    const int* __restrict__ edst,
    const float* __restrict__ ew,
    float* __restrict__ agg,
    int nE)
{
    long long tid = (long long)blockIdx.x * 256 + threadIdx.x;
    int e = (int)(tid >> 5);
    if (e >= nE) return;
    int c = ((int)tid & 31) << 2;

    int s = esrc[e];
    int d = edst[e];
    float w = ew[e];

    const float4 hv = *reinterpret_cast<const float4*>(h + (size_t)s * D + c);
    float* o = agg + (size_t)d * D + c;
    atomicAdd(o + 0, hv.x * w);
    atomicAdd(o + 1, hv.y * w);
    atomicAdd(o + 2, hv.z * w);
    atomicAdd(o + 3, hv.w * w);
}

// ---------------------------------------------------------------------------
// Kernel 2: out = relu(agg @ W + b), computed IN-PLACE (agg == out).
// In-place safety: each block's output rows depend only on the same rows of
// agg; every global read of the A-tile happens during staging, before the
// __syncthreads() that precedes any compute/store. Blocks touch disjoint rows
// (the tail-clamp row N-1 belongs to the last block itself).
// Tile: BM=64 rows x BN=128 cols (full N), BK=32. 256 threads.
// Thread (tx,ty) = (t&31, t>>5): owns 8 rows (ty*8+i) x 4 cols (tx*4) = float4.
// LDS: sA transposed [32][64] (A-frag reads are 2-address broadcasts,
// conflict-free), sB [32][128] (b128 stride-1 reads, conflict-free).
// ---------------------------------------------------------------------------
__global__ __launch_bounds__(256) void gcn_gemm_bias_relu(
    const float* __restrict__ A,     // [N][128] aggregated h (== out)
    const float* __restrict__ W,     // [128][128]
    const float* __restrict__ bias,  // [128]
    float* __restrict__ out,         // [N][128]
    int N)
{
    __shared__ float sA[32][64];
    __shared__ float sB[32][128];

    int t  = threadIdx.x;
    int tx = t & 31;
    int ty = t >> 5;
    int r0 = blockIdx.x * 64;

    float4 acc[8];
#pragma unroll
    for (int i = 0; i < 8; ++i) acc[i] = make_float4(0.f, 0.f, 0.f, 0.f);

    for (int kc = 0; kc < 4; ++kc) {
        // Stage A chunk: rows r0..r0+63, k-cols kc*32..kc*32+31 (transposed)
#pragma unroll
        for (int it = 0; it < 2; ++it) {
            int r   = (t >> 3) + it * 32;
            int kk  = (t & 7) * 4;
            int row = r0 + r;
            int rowc = row < N ? row : N - 1;   // clamp: value unused, row owned by this block
            float4 v = *reinterpret_cast<const float4*>(
                A + (size_t)rowc * D + kc * 32 + kk);
            sA[kk + 0][r] = v.x;
            sA[kk + 1][r] = v.y;
            sA[kk + 2][r] = v.z;
            sA[kk + 3][r] = v.w;
        }
        // Stage B chunk: W rows kc*32..+31, all 128 cols
#pragma unroll
        for (int it = 0; it < 4; ++it) {
            int g  = t + it * 256;
            int k  = g >> 5;
            int cc = (g & 31) * 4;
            *reinterpret_cast<float4*>(&sB[k][cc]) =
                *reinterpret_cast<const float4*>(W + (size_t)(kc * 32 + k) * D + cc);
        }
        __syncthreads();

#pragma unroll
        for (int kk = 0; kk < 32; ++kk) {
            float4 bv = *reinterpret_cast<const float4*>(&sB[kk][tx * 4]);
#pragma unroll
            for (int i = 0; i < 8; ++i) {
                float a = sA[kk][ty * 8 + i];   // contiguous over i -> vectorizes
                acc[i].x += a * bv.x;
                acc[i].y += a * bv.y;
                acc[i].z += a * bv.z;
                acc[i].w += a * bv.w;
            }
        }
        __syncthreads();
    }

    float4 bb = *reinterpret_cast<const float4*>(bias + tx * 4);
#pragma unroll
    for (int i = 0; i < 8; ++i) {
        int row = r0 + ty * 8 + i;
        if (row < N) {
            float4 v;
            v.x = fmaxf(acc[i].x + bb.x, 0.f);
            v.y = fmaxf(acc[i].y + bb.y, 0.f);
            v.z = fmaxf(acc[i].z + bb.z, 0.f);
            v.w = fmaxf(acc[i].w + bb.w, 0.f);
            *reinterpret_cast<float4*>(out + (size_t)row * D + tx * 4) = v;
        }
    }
}

// ---------------------------------------------------------------------------
extern "C" void kernel_launch(void* const* d_in, const int* in_sizes, int n_in,
                              void* d_out, int out_size, void* d_ws, size_t ws_size,
                              hipStream_t stream)
{
    const float* h    = (const float*)d_in[0];
    const int*   esrc = (const int*)  d_in[1];
    const int*   edst = (const int*)  d_in[2];
    const float* ew   = (const float*)d_in[3];
    const float* W    = (const float*)d_in[4];
    const float* bias = (const float*)d_in[5];
    float* out = (float*)d_out;

    const int nE = in_sizes[1];
    const int N  = in_sizes[0] / D;

    // agg accumulates directly in d_out (poisoned 0xAA each call -> zero it)
    hipMemsetAsync(d_out, 0, (size_t)out_size * sizeof(float), stream);

    // Scatter: nE edges * 32 lanes each
    long long scatterThreads = (long long)nE * 32;
    int scatterBlocks = (int)((scatterThreads + 255) / 256);
    gcn_scatter<<<scatterBlocks, 256, 0, stream>>>(h, esrc, edst, ew, out, nE);

    // In-place GEMM + bias + relu
    int gemmBlocks = (N + 63) / 64;
    gcn_gemm_bias_relu<<<gemmBlocks, 256, 0, stream>>>(out, W, bias, out, N);
}

// Round 2
// 434.026 us; speedup vs baseline: 6.4940x; 6.4940x over previous
//
#include <hip/hip_runtime.h>

#define D 128

// ===========================================================================
// CSR-build pipeline (counting sort by edge_dst), then atomic-free gather.
// ws layout: off[N+1] | deg[N] | cursor[N] | blksums[256] | ssrc[E] | sw[E]
// ===========================================================================

// ---- 1. histogram of dst --------------------------------------------------
__global__ __launch_bounds__(256) void hist_kernel(
    const int* __restrict__ edst, int* __restrict__ deg, int nE)
{
    int e = blockIdx.x * 256 + threadIdx.x;
    if (e < nE) atomicAdd(&deg[edst[e]], 1);
}

// ---- 2. exclusive scan over deg[N] -> off[N], cursor[N] -------------------
#define SCAN_BLK 1024  // elements per block (256 threads x 4)

__global__ __launch_bounds__(256) void scan_pass1(
    const int* __restrict__ deg, int* __restrict__ blksums, int N)
{
    __shared__ int s[256];
    int t = threadIdx.x;
    int base = blockIdx.x * SCAN_BLK + t * 4;
    int sum = 0;
#pragma unroll
    for (int i = 0; i < 4; ++i) {
        int idx = base + i;
        if (idx < N) sum += deg[idx];
    }
    s[t] = sum;
    __syncthreads();
    for (int o = 128; o > 0; o >>= 1) {
        if (t < o) s[t] += s[t + o];
        __syncthreads();
    }
    if (t == 0) blksums[blockIdx.x] = s[0];
}

__global__ __launch_bounds__(256) void scan_pass2(int* __restrict__ blksums, int nblk)
{
    // single block; nblk <= 256
    __shared__ int s[256];
    int t = threadIdx.x;
    int v = (t < nblk) ? blksums[t] : 0;
    s[t] = v;
    __syncthreads();
    for (int o = 1; o < 256; o <<= 1) {
        int add = (t >= o) ? s[t - o] : 0;
        __syncthreads();
        s[t] += add;
        __syncthreads();
    }
    if (t < nblk) blksums[t] = s[t] - v;   // exclusive
}

__global__ __launch_bounds__(256) void scan_pass3(
    const int* __restrict__ deg, const int* __restrict__ blksums,
    int* __restrict__ off, int* __restrict__ cursor, int N)
{
    __shared__ int s[256];
    int t = threadIdx.x;
    int base = blockIdx.x * SCAN_BLK + t * 4;
    int v[4];
    int sum = 0;
#pragma unroll
    for (int i = 0; i < 4; ++i) {
        int idx = base + i;
        v[i] = (idx < N) ? deg[idx] : 0;
        sum += v[i];
    }
    s[t] = sum;
    __syncthreads();
    int mine = sum;
    for (int o = 1; o < 256; o <<= 1) {
        int add = (t >= o) ? s[t - o] : 0;
        __syncthreads();
        s[t] += add;
        __syncthreads();
    }
    int run = s[t] - mine + blksums[blockIdx.x];
#pragma unroll
    for (int i = 0; i < 4; ++i) {
        int idx = base + i;
        if (idx < N) {
            off[idx]    = run;
            cursor[idx] = run;
            run += v[i];
        }
    }
}

// ---- 3. permute edges into dst-sorted order -------------------------------
__global__ __launch_bounds__(256) void scatter_edges(
    const int* __restrict__ esrc, const int* __restrict__ edst,
    const float* __restrict__ ew, int* __restrict__ cursor,
    int* __restrict__ ssrc, float* __restrict__ sw, int nE)
{
    int e = blockIdx.x * 256 + threadIdx.x;
    if (e < nE) {
        int d = edst[e];
        int pos = atomicAdd(&cursor[d], 1);
        ssrc[pos] = esrc[e];
        sw[pos]   = ew[e];
    }
}

// ---- 4. atomic-free gather: agg[n] = sum_j w_j * h[src_j] -----------------
// 32 lanes per node, float4 per lane (128 cols). 2-deep unroll overlaps the
// dependent ssrc->h gather latency chains.
__global__ __launch_bounds__(256) void gcn_gather(
    const float* __restrict__ h, const int* __restrict__ off,
    const int* __restrict__ ssrc, const float* __restrict__ sw,
    float* __restrict__ agg, int N, int E)
{
    int gid = blockIdx.x * 256 + threadIdx.x;
    int node = gid >> 5;
    if (node >= N) return;
    int c = (gid & 31) << 2;

    int beg = off[node];
    int end = (node + 1 < N) ? off[node + 1] : E;

    float4 acc = make_float4(0.f, 0.f, 0.f, 0.f);
    int j = beg;
    for (; j + 1 < end; j += 2) {
        int   s0 = ssrc[j],     s1 = ssrc[j + 1];
        float w0 = sw[j],       w1 = sw[j + 1];
        const float4 h0 = *reinterpret_cast<const float4*>(h + (size_t)s0 * D + c);
        const float4 h1 = *reinterpret_cast<const float4*>(h + (size_t)s1 * D + c);
        acc.x += w0 * h0.x + w1 * h1.x;
        acc.y += w0 * h0.y + w1 * h1.y;
        acc.z += w0 * h0.z + w1 * h1.z;
        acc.w += w0 * h0.w + w1 * h1.w;
    }
    if (j < end) {
        int   s0 = ssrc[j];
        float w0 = sw[j];
        const float4 h0 = *reinterpret_cast<const float4*>(h + (size_t)s0 * D + c);
        acc.x += w0 * h0.x;
        acc.y += w0 * h0.y;
        acc.z += w0 * h0.z;
        acc.w += w0 * h0.w;
    }
    *reinterpret_cast<float4*>(agg + (size_t)node * D + c) = acc;
}

// ---- fallback: original atomic scatter (used only if ws too small) --------
__global__ __launch_bounds__(256) void gcn_scatter(
    const float* __restrict__ h, const int* __restrict__ esrc,
    const int* __restrict__ edst, const float* __restrict__ ew,
    float* __restrict__ agg, int nE)
{
    long long tid = (long long)blockIdx.x * 256 + threadIdx.x;
    int e = (int)(tid >> 5);
    if (e >= nE) return;
    int c = ((int)tid & 31) << 2;
    int s = esrc[e];
    int d = edst[e];
    float w = ew[e];
    const float4 hv = *reinterpret_cast<const float4*>(h + (size_t)s * D + c);
    float* o = agg + (size_t)d * D + c;
    atomicAdd(o + 0, hv.x * w);
    atomicAdd(o + 1, hv.y * w);
    atomicAdd(o + 2, hv.z * w);
    atomicAdd(o + 3, hv.w * w);
}

// ---------------------------------------------------------------------------
// out = relu(agg @ W + b), IN-PLACE (agg == out). Each block's output rows
// depend only on the same rows of agg; all global A reads happen during
// staging before compute/store. Tile 64x128, BK=32, 256 threads, 8x4 regs.
// ---------------------------------------------------------------------------
__global__ __launch_bounds__(256) void gcn_gemm_bias_relu(
    const float* __restrict__ A, const float* __restrict__ W,
    const float* __restrict__ bias, float* __restrict__ out, int N)
{
    __shared__ float sA[32][64];
    __shared__ float sB[32][128];

    int t  = threadIdx.x;
    int tx = t & 31;
    int ty = t >> 5;
    int r0 = blockIdx.x * 64;

    float4 acc[8];
#pragma unroll
    for (int i = 0; i < 8; ++i) acc[i] = make_float4(0.f, 0.f, 0.f, 0.f);

    for (int kc = 0; kc < 4; ++kc) {
#pragma unroll
        for (int it = 0; it < 2; ++it) {
            int r    = (t >> 3) + it * 32;
            int kk   = (t & 7) * 4;
            int row  = r0 + r;
            int rowc = row < N ? row : N - 1;
            float4 v = *reinterpret_cast<const float4*>(
                A + (size_t)rowc * D + kc * 32 + kk);
            sA[kk + 0][r] = v.x;
            sA[kk + 1][r] = v.y;
            sA[kk + 2][r] = v.z;
            sA[kk + 3][r] = v.w;
        }
#pragma unroll
        for (int it = 0; it < 4; ++it) {
            int g  = t + it * 256;
            int k  = g >> 5;
            int cc = (g & 31) * 4;
            *reinterpret_cast<float4*>(&sB[k][cc]) =
                *reinterpret_cast<const float4*>(W + (size_t)(kc * 32 + k) * D + cc);
        }
        __syncthreads();

#pragma unroll
        for (int kk = 0; kk < 32; ++kk) {
            float4 bv = *reinterpret_cast<const float4*>(&sB[kk][tx * 4]);
#pragma unroll
            for (int i = 0; i < 8; ++i) {
                float a = sA[kk][ty * 8 + i];
                acc[i].x += a * bv.x;
                acc[i].y += a * bv.y;
                acc[i].z += a * bv.z;
                acc[i].w += a * bv.w;
            }
        }
        __syncthreads();
    }

    float4 bb = *reinterpret_cast<const float4*>(bias + tx * 4);
#pragma unroll
    for (int i = 0; i < 8; ++i) {
        int row = r0 + ty * 8 + i;
        if (row < N) {
            float4 v;
            v.x = fmaxf(acc[i].x + bb.x, 0.f);
            v.y = fmaxf(acc[i].y + bb.y, 0.f);
            v.z = fmaxf(acc[i].z + bb.z, 0.f);
            v.w = fmaxf(acc[i].w + bb.w, 0.f);
            *reinterpret_cast<float4*>(out + (size_t)row * D + tx * 4) = v;
        }
    }
}

// ---------------------------------------------------------------------------
extern "C" void kernel_launch(void* const* d_in, const int* in_sizes, int n_in,
                              void* d_out, int out_size, void* d_ws, size_t ws_size,
                              hipStream_t stream)
{
    const float* h    = (const float*)d_in[0];
    const int*   esrc = (const int*)  d_in[1];
    const int*   edst = (const int*)  d_in[2];
    const float* ew   = (const float*)d_in[3];
    const float* W    = (const float*)d_in[4];
    const float* bias = (const float*)d_in[5];
    float* out = (float*)d_out;

    const int nE = in_sizes[1];
    const int N  = in_sizes[0] / D;

    const size_t need = ((size_t)(N + 1) + N + N + 256 + nE) * 4 + (size_t)nE * 4;
    const int nblkScan = (N + SCAN_BLK - 1) / SCAN_BLK;

    if (ws_size >= need && nblkScan <= 256) {
        // ---- CSR path -----------------------------------------------------
        int*   off     = (int*)d_ws;
        int*   deg     = off + (N + 1);
        int*   cursor  = deg + N;
        int*   blksums = cursor + N;
        int*   ssrc    = blksums + 256;
        float* sw      = (float*)(ssrc + nE);

        hipMemsetAsync(deg, 0, (size_t)N * sizeof(int), stream);

        int eBlocks = (nE + 255) / 256;
        hist_kernel<<<eBlocks, 256, 0, stream>>>(edst, deg, nE);
        scan_pass1<<<nblkScan, 256, 0, stream>>>(deg, blksums, N);
        scan_pass2<<<1, 256, 0, stream>>>(blksums, nblkScan);
        scan_pass3<<<nblkScan, 256, 0, stream>>>(deg, blksums, off, cursor, N);
        scatter_edges<<<eBlocks, 256, 0, stream>>>(esrc, edst, ew, cursor, ssrc, sw, nE);

        int gatherBlocks = (N * 32 + 255) / 256;
        gcn_gather<<<gatherBlocks, 256, 0, stream>>>(h, off, ssrc, sw, out, N, nE);
    } else {
        // ---- fallback: atomic scatter ------------------------------------
        hipMemsetAsync(d_out, 0, (size_t)out_size * sizeof(float), stream);
        long long scatterThreads = (long long)nE * 32;
        int scatterBlocks = (int)((scatterThreads + 255) / 256);
        gcn_scatter<<<scatterBlocks, 256, 0, stream>>>(h, esrc, edst, ew, out, nE);
    }

    int gemmBlocks = (N + 63) / 64;
    gcn_gemm_bias_relu<<<gemmBlocks, 256, 0, stream>>>(out, W, bias, out, N);
}

// Round 3
// 428.004 us; speedup vs baseline: 6.5854x; 1.0141x over previous
//
#include <hip/hip_runtime.h>

#define D 128

// f32 -> bf16 round-to-nearest-even (bit trick, no header dependency)
static __device__ __forceinline__ unsigned short f2bf(float f) {
    unsigned u = __float_as_uint(f);
    unsigned r = (u + 0x7FFFu + ((u >> 16) & 1u)) >> 16;
    return (unsigned short)r;
}
static __device__ __forceinline__ float bf2f(unsigned short b) {
    return __uint_as_float(((unsigned)b) << 16);
}

// ===========================================================================
// Pipeline: x = h@W (bf16, ws) ; CSR build (counting sort by dst) ;
//           out = relu(gather_sum(x) + b)
// ===========================================================================

// ---- 1. histogram of dst --------------------------------------------------
__global__ __launch_bounds__(256) void hist_kernel(
    const int* __restrict__ edst, int* __restrict__ deg, int nE)
{
    int e = blockIdx.x * 256 + threadIdx.x;
    if (e < nE) atomicAdd(&deg[edst[e]], 1);
}

// ---- 2. exclusive scan over deg[N] -> off[N], cursor[N] -------------------
#define SCAN_BLK 1024  // elements per block (256 threads x 4)

__global__ __launch_bounds__(256) void scan_pass1(
    const int* __restrict__ deg, int* __restrict__ blksums, int N)
{
    __shared__ int s[256];
    int t = threadIdx.x;
    int base = blockIdx.x * SCAN_BLK + t * 4;
    int sum = 0;
#pragma unroll
    for (int i = 0; i < 4; ++i) {
        int idx = base + i;
        if (idx < N) sum += deg[idx];
    }
    s[t] = sum;
    __syncthreads();
    for (int o = 128; o > 0; o >>= 1) {
        if (t < o) s[t] += s[t + o];
        __syncthreads();
    }
    if (t == 0) blksums[blockIdx.x] = s[0];
}

__global__ __launch_bounds__(256) void scan_pass2(int* __restrict__ blksums, int nblk)
{
    __shared__ int s[256];
    int t = threadIdx.x;
    int v = (t < nblk) ? blksums[t] : 0;
    s[t] = v;
    __syncthreads();
    for (int o = 1; o < 256; o <<= 1) {
        int add = (t >= o) ? s[t - o] : 0;
        __syncthreads();
        s[t] += add;
        __syncthreads();
    }
    if (t < nblk) blksums[t] = s[t] - v;   // exclusive
}

__global__ __launch_bounds__(256) void scan_pass3(
    const int* __restrict__ deg, const int* __restrict__ blksums,
    int* __restrict__ off, int* __restrict__ cursor, int N)
{
    __shared__ int s[256];
    int t = threadIdx.x;
    int base = blockIdx.x * SCAN_BLK + t * 4;
    int v[4];
    int sum = 0;
#pragma unroll
    for (int i = 0; i < 4; ++i) {
        int idx = base + i;
        v[i] = (idx < N) ? deg[idx] : 0;
        sum += v[i];
    }
    s[t] = sum;
    __syncthreads();
    int mine = sum;
    for (int o = 1; o < 256; o <<= 1) {
        int add = (t >= o) ? s[t - o] : 0;
        __syncthreads();
        s[t] += add;
        __syncthreads();
    }
    int run = s[t] - mine + blksums[blockIdx.x];
#pragma unroll
    for (int i = 0; i < 4; ++i) {
        int idx = base + i;
        if (idx < N) {
            off[idx]    = run;
            cursor[idx] = run;
            run += v[i];
        }
    }
}

// ---- 3. permute edges into dst-sorted order, packed (src, w) --------------
__global__ __launch_bounds__(256) void scatter_edges(
    const int* __restrict__ esrc, const int* __restrict__ edst,
    const float* __restrict__ ew, int* __restrict__ cursor,
    int2* __restrict__ epack, int nE)
{
    int e = blockIdx.x * 256 + threadIdx.x;
    if (e < nE) {
        int d = edst[e];
        int pos = atomicAdd(&cursor[d], 1);
        epack[pos] = make_int2(esrc[e], __float_as_int(ew[e]));
    }
}

// ---------------------------------------------------------------------------
// 4. GEMM: x = h @ W, fp32 accumulate, bf16 store to ws.
// Tile 64x128, BK=32, 256 threads, 8 rows x 4 cols per thread.
// ---------------------------------------------------------------------------
__global__ __launch_bounds__(256) void gcn_gemm_bf16(
    const float* __restrict__ A, const float* __restrict__ W,
    unsigned short* __restrict__ xb, int N)
{
    __shared__ float sA[32][64];
    __shared__ float sB[32][128];

    int t  = threadIdx.x;
    int tx = t & 31;
    int ty = t >> 5;
    int r0 = blockIdx.x * 64;

    float4 acc[8];
#pragma unroll
    for (int i = 0; i < 8; ++i) acc[i] = make_float4(0.f, 0.f, 0.f, 0.f);

    for (int kc = 0; kc < 4; ++kc) {
#pragma unroll
        for (int it = 0; it < 2; ++it) {
            int r    = (t >> 3) + it * 32;
            int kk   = (t & 7) * 4;
            int row  = r0 + r;
            int rowc = row < N ? row : N - 1;
            float4 v = *reinterpret_cast<const float4*>(
                A + (size_t)rowc * D + kc * 32 + kk);
            sA[kk + 0][r] = v.x;
            sA[kk + 1][r] = v.y;
            sA[kk + 2][r] = v.z;
            sA[kk + 3][r] = v.w;
        }
#pragma unroll
        for (int it = 0; it < 4; ++it) {
            int g  = t + it * 256;
            int k  = g >> 5;
            int cc = (g & 31) * 4;
            *reinterpret_cast<float4*>(&sB[k][cc]) =
                *reinterpret_cast<const float4*>(W + (size_t)(kc * 32 + k) * D + cc);
        }
        __syncthreads();

#pragma unroll
        for (int kk = 0; kk < 32; ++kk) {
            float4 bv = *reinterpret_cast<const float4*>(&sB[kk][tx * 4]);
#pragma unroll
            for (int i = 0; i < 8; ++i) {
                float a = sA[kk][ty * 8 + i];
                acc[i].x += a * bv.x;
                acc[i].y += a * bv.y;
                acc[i].z += a * bv.z;
                acc[i].w += a * bv.w;
            }
        }
        __syncthreads();
    }

#pragma unroll
    for (int i = 0; i < 8; ++i) {
        int row = r0 + ty * 8 + i;
        if (row < N) {
            ushort4 q;
            q.x = f2bf(acc[i].x);
            q.y = f2bf(acc[i].y);
            q.z = f2bf(acc[i].z);
            q.w = f2bf(acc[i].w);
            *reinterpret_cast<ushort4*>(xb + (size_t)row * D + tx * 4) = q;
        }
    }
}

// ---------------------------------------------------------------------------
// 5. Gather: out[n] = relu( sum_j w_j * x[src_j] + b ), x in bf16.
// 32 lanes per node, ushort4 (4 bf16 cols) per lane. 4-edge unroll for ILP.
// ---------------------------------------------------------------------------
__global__ __launch_bounds__(256) void gcn_gather_bf16(
    const unsigned short* __restrict__ xb, const int* __restrict__ off,
    const int2* __restrict__ epack, const float* __restrict__ bias,
    float* __restrict__ out, int N, int E)
{
    int gid = blockIdx.x * 256 + threadIdx.x;
    int node = gid >> 5;
    if (node >= N) return;
    int c = (gid & 31) << 2;

    int beg = off[node];
    int end = (node + 1 < N) ? off[node + 1] : E;

    float4 acc = make_float4(0.f, 0.f, 0.f, 0.f);
    int j = beg;
    for (; j + 3 < end; j += 4) {
        int2 e0 = epack[j], e1 = epack[j + 1], e2 = epack[j + 2], e3 = epack[j + 3];
        ushort4 q0 = *reinterpret_cast<const ushort4*>(xb + (size_t)e0.x * D + c);
        ushort4 q1 = *reinterpret_cast<const ushort4*>(xb + (size_t)e1.x * D + c);
        ushort4 q2 = *reinterpret_cast<const ushort4*>(xb + (size_t)e2.x * D + c);
        ushort4 q3 = *reinterpret_cast<const ushort4*>(xb + (size_t)e3.x * D + c);
        float w0 = __int_as_float(e0.y), w1 = __int_as_float(e1.y);
        float w2 = __int_as_float(e2.y), w3 = __int_as_float(e3.y);
        acc.x += w0 * bf2f(q0.x) + w1 * bf2f(q1.x) + w2 * bf2f(q2.x) + w3 * bf2f(q3.x);
        acc.y += w0 * bf2f(q0.y) + w1 * bf2f(q1.y) + w2 * bf2f(q2.y) + w3 * bf2f(q3.y);
        acc.z += w0 * bf2f(q0.z) + w1 * bf2f(q1.z) + w2 * bf2f(q2.z) + w3 * bf2f(q3.z);
        acc.w += w0 * bf2f(q0.w) + w1 * bf2f(q1.w) + w2 * bf2f(q2.w) + w3 * bf2f(q3.w);
    }
    for (; j < end; ++j) {
        int2 e0 = epack[j];
        ushort4 q0 = *reinterpret_cast<const ushort4*>(xb + (size_t)e0.x * D + c);
        float w0 = __int_as_float(e0.y);
        acc.x += w0 * bf2f(q0.x);
        acc.y += w0 * bf2f(q0.y);
        acc.z += w0 * bf2f(q0.z);
        acc.w += w0 * bf2f(q0.w);
    }

    float4 bb = *reinterpret_cast<const float4*>(bias + c);
    float4 v;
    v.x = fmaxf(acc.x + bb.x, 0.f);
    v.y = fmaxf(acc.y + bb.y, 0.f);
    v.z = fmaxf(acc.z + bb.z, 0.f);
    v.w = fmaxf(acc.w + bb.w, 0.f);
    *reinterpret_cast<float4*>(out + (size_t)node * D + c) = v;
}

// ===========================================================================
// Fallback path (ws too small): atomic scatter + in-place fp32 GEMM+epilogue
// ===========================================================================
__global__ __launch_bounds__(256) void gcn_scatter(
    const float* __restrict__ h, const int* __restrict__ esrc,
    const int* __restrict__ edst, const float* __restrict__ ew,
    float* __restrict__ agg, int nE)
{
    long long tid = (long long)blockIdx.x * 256 + threadIdx.x;
    int e = (int)(tid >> 5);
    if (e >= nE) return;
    int c = ((int)tid & 31) << 2;
    int s = esrc[e];
    int d = edst[e];
    float w = ew[e];
    const float4 hv = *reinterpret_cast<const float4*>(h + (size_t)s * D + c);
    float* o = agg + (size_t)d * D + c;
    atomicAdd(o + 0, hv.x * w);
    atomicAdd(o + 1, hv.y * w);
    atomicAdd(o + 2, hv.z * w);
    atomicAdd(o + 3, hv.w * w);
}

__global__ __launch_bounds__(256) void gcn_gemm_bias_relu(
    const float* __restrict__ A, const float* __restrict__ W,
    const float* __restrict__ bias, float* __restrict__ out, int N)
{
    __shared__ float sA[32][64];
    __shared__ float sB[32][128];

    int t  = threadIdx.x;
    int tx = t & 31;
    int ty = t >> 5;
    int r0 = blockIdx.x * 64;

    float4 acc[8];
#pragma unroll
    for (int i = 0; i < 8; ++i) acc[i] = make_float4(0.f, 0.f, 0.f, 0.f);

    for (int kc = 0; kc < 4; ++kc) {
#pragma unroll
        for (int it = 0; it < 2; ++it) {
            int r    = (t >> 3) + it * 32;
            int kk   = (t & 7) * 4;
            int row  = r0 + r;
            int rowc = row < N ? row : N - 1;
            float4 v = *reinterpret_cast<const float4*>(
                A + (size_t)rowc * D + kc * 32 + kk);
            sA[kk + 0][r] = v.x;
            sA[kk + 1][r] = v.y;
            sA[kk + 2][r] = v.z;
            sA[kk + 3][r] = v.w;
        }
#pragma unroll
        for (int it = 0; it < 4; ++it) {
            int g  = t + it * 256;
            int k  = g >> 5;
            int cc = (g & 31) * 4;
            *reinterpret_cast<float4*>(&sB[k][cc]) =
                *reinterpret_cast<const float4*>(W + (size_t)(kc * 32 + k) * D + cc);
        }
        __syncthreads();

#pragma unroll
        for (int kk = 0; kk < 32; ++kk) {
            float4 bv = *reinterpret_cast<const float4*>(&sB[kk][tx * 4]);
#pragma unroll
            for (int i = 0; i < 8; ++i) {
                float a = sA[kk][ty * 8 + i];
                acc[i].x += a * bv.x;
                acc[i].y += a * bv.y;
                acc[i].z += a * bv.z;
                acc[i].w += a * bv.w;
            }
        }
        __syncthreads();
    }

    float4 bb = *reinterpret_cast<const float4*>(bias + tx * 4);
#pragma unroll
    for (int i = 0; i < 8; ++i) {
        int row = r0 + ty * 8 + i;
        if (row < N) {
            float4 v;
            v.x = fmaxf(acc[i].x + bb.x, 0.f);
            v.y = fmaxf(acc[i].y + bb.y, 0.f);
            v.z = fmaxf(acc[i].z + bb.z, 0.f);
            v.w = fmaxf(acc[i].w + bb.w, 0.f);
            *reinterpret_cast<float4*>(out + (size_t)row * D + tx * 4) = v;
        }
    }
}

// ---------------------------------------------------------------------------
extern "C" void kernel_launch(void* const* d_in, const int* in_sizes, int n_in,
                              void* d_out, int out_size, void* d_ws, size_t ws_size,
                              hipStream_t stream)
{
    const float* h    = (const float*)d_in[0];
    const int*   esrc = (const int*)  d_in[1];
    const int*   edst = (const int*)  d_in[2];
    const float* ew   = (const float*)d_in[3];
    const float* W    = (const float*)d_in[4];
    const float* bias = (const float*)d_in[5];
    float* out = (float*)d_out;

    const int nE = in_sizes[1];
    const int N  = in_sizes[0] / D;
    const int nblkScan = (N + SCAN_BLK - 1) / SCAN_BLK;

    // ws layout: off[N+1] | deg[N] | cursor[N] | blksums[256] | epack[E] (8B) | xb[N*128] (bf16)
    char* base = (char*)d_ws;
    size_t intBytes = ((size_t)(N + 1) + N + N + 256) * 4;
    size_t o1 = (intBytes + 15) & ~(size_t)15;
    size_t o2 = (o1 + (size_t)nE * 8 + 15) & ~(size_t)15;
    size_t need = o2 + (size_t)N * D * 2;

    if (ws_size >= need && nblkScan <= 256) {
        int*  off     = (int*)base;
        int*  deg     = off + (N + 1);
        int*  cursor  = deg + N;
        int*  blksums = cursor + N;
        int2* epack   = (int2*)(base + o1);
        unsigned short* xb = (unsigned short*)(base + o2);

        hipMemsetAsync(deg, 0, (size_t)N * sizeof(int), stream);

        int eBlocks = (nE + 255) / 256;
        hist_kernel<<<eBlocks, 256, 0, stream>>>(edst, deg, nE);
        scan_pass1<<<nblkScan, 256, 0, stream>>>(deg, blksums, N);
        scan_pass2<<<1, 256, 0, stream>>>(blksums, nblkScan);
        scan_pass3<<<nblkScan, 256, 0, stream>>>(deg, blksums, off, cursor, N);
        scatter_edges<<<eBlocks, 256, 0, stream>>>(esrc, edst, ew, cursor, epack, nE);

        int gemmBlocks = (N + 63) / 64;
        gcn_gemm_bf16<<<gemmBlocks, 256, 0, stream>>>(h, W, xb, N);

        int gatherBlocks = (N * 32 + 255) / 256;
        gcn_gather_bf16<<<gatherBlocks, 256, 0, stream>>>(xb, off, epack, bias, out, N, nE);
    } else {
        hipMemsetAsync(d_out, 0, (size_t)out_size * sizeof(float), stream);
        long long scatterThreads = (long long)nE * 32;
        int scatterBlocks = (int)((scatterThreads + 255) / 256);
        gcn_scatter<<<scatterBlocks, 256, 0, stream>>>(h, esrc, edst, ew, out, nE);
        int gemmBlocks = (N + 63) / 64;
        gcn_gemm_bias_relu<<<gemmBlocks, 256, 0, stream>>>(out, W, bias, out, N);
    }
}

// Round 4
// 291.579 us; speedup vs baseline: 9.6666x; 1.4679x over previous
//
#include <hip/hip_runtime.h>

#define D 128
#define SRCBITS 17          // 100000 < 2^17
#define SRCMASK ((1 << SRCBITS) - 1)
#define CBITS 8             // 256 nodes per coarse bucket
#define CNODES 256
#define GNODES 128          // output nodes per gather block (half a coarse bucket)
#define CAPD 4096           // LDS sort capacity in fused gather (mean 2048, ~45 sigma)
#define CHUNK_A 4096
#define CHUNK_C 3072

// f32 -> bf16 round-to-nearest-even
static __device__ __forceinline__ unsigned short f2bf(float f) {
    unsigned u = __float_as_uint(f);
    unsigned r = (u + 0x7FFFu + ((u >> 16) & 1u)) >> 16;
    return (unsigned short)r;
}
static __device__ __forceinline__ float bf2f(unsigned short b) {
    return __uint_as_float(((unsigned)b) << 16);
}

// ===========================================================================
// A. coarse histogram: ccount[b] = #edges with (dst>>8)==b. LDS-staged.
// ===========================================================================
__global__ __launch_bounds__(256) void coarse_hist(
    const int* __restrict__ edst, int* __restrict__ ccount, int nE, int NB)
{
    __shared__ int lh[512];
    int t = threadIdx.x;
    for (int i = t; i < 512; i += 256) lh[i] = 0;
    __syncthreads();
    int e0 = blockIdx.x * CHUNK_A;
    for (int i = t; i < CHUNK_A; i += 256) {
        int e = e0 + i;
        if (e < nE) atomicAdd(&lh[edst[e] >> CBITS], 1);
    }
    __syncthreads();
    for (int i = t; i < NB; i += 256) {
        int v = lh[i];
        if (v > 0) atomicAdd(&ccount[i], v);
    }
}

// ===========================================================================
// B. scan over NB (<=512) buckets -> cstart[NB+1], ccur init. Single block.
// ===========================================================================
__global__ __launch_bounds__(512) void coarse_scan(
    const int* __restrict__ ccount, int* __restrict__ cstart,
    int* __restrict__ ccur, int NB, int nE)
{
    __shared__ int tmp[512];
    int t = threadIdx.x;
    tmp[t] = (t < NB) ? ccount[t] : 0;
    __syncthreads();
    for (int off = 1; off < 512; off <<= 1) {
        int v = (t >= off) ? tmp[t - off] : 0;
        __syncthreads();
        tmp[t] += v;
        __syncthreads();
    }
    if (t < NB) {
        int ex = (t == 0) ? 0 : tmp[t - 1];
        cstart[t] = ex;
        ccur[t]   = ex;
    }
    if (t == 0) cstart[NB] = nE;
}

// ===========================================================================
// C. bucket scatter with write-coalescing: block stages CHUNK_C edges in LDS,
//    local counting-sort by coarse bucket, reserves global runs (1 atomic per
//    block*bucket), then writes runs position-ordered (coalesced ~1-line runs).
//    Payload: int2( src | (dst&255)<<17 , bits(w) ).
// ===========================================================================
__global__ __launch_bounds__(256) void bucket_scatter(
    const int* __restrict__ esrc, const int* __restrict__ edst,
    const float* __restrict__ ew, int* __restrict__ ccur,
    int2* __restrict__ epack, int nE)
{
    __shared__ int2 stage[CHUNK_C];
    __shared__ int2 sorted[CHUNK_C];
    __shared__ unsigned short bidx[CHUNK_C];
    __shared__ unsigned short runid[CHUNK_C];
    __shared__ int lhist[512];   // counts -> inclusive scan
    __shared__ int lbase[512];   // exclusive bases
    __shared__ int lcur[512];
    __shared__ int delta[512];   // gbase - lbase

    int t = threadIdx.x;
    for (int i = t; i < 512; i += 256) lhist[i] = 0;
    __syncthreads();

    int e0 = blockIdx.x * CHUNK_C;
    for (int i = t; i < CHUNK_C; i += 256) {
        int e = e0 + i;
        if (e < nE) {
            int s = esrc[e], d = edst[e];
            stage[i] = make_int2(s | ((d & (CNODES - 1)) << SRCBITS),
                                 __float_as_int(ew[e]));
            int b = d >> CBITS;
            bidx[i] = (unsigned short)b;
            atomicAdd(&lhist[b], 1);
        } else {
            stage[i].x = -1;
        }
    }
    __syncthreads();

    // inclusive Hillis-Steele scan of lhist[0..511], 2 slots per thread
    for (int off = 1; off < 512; off <<= 1) {
        int i0 = t, i1 = t + 256;
        int v0 = (i0 >= off) ? lhist[i0 - off] : 0;
        int v1 = (i1 >= off) ? lhist[i1 - off] : 0;
        __syncthreads();
        lhist[i0] += v0;
        lhist[i1] += v1;
        __syncthreads();
    }
    for (int i = t; i < 512; i += 256) {
        int ex = (i == 0) ? 0 : lhist[i - 1];
        lbase[i] = ex;
        lcur[i]  = ex;
    }
    __syncthreads();

    // reserve global runs
    for (int b = t; b < 512; b += 256) {
        int cnt = lhist[b] - lbase[b];
        if (cnt > 0) {
            int g = atomicAdd(&ccur[b], cnt);
            delta[b] = g - lbase[b];
        }
    }
    __syncthreads();

    // local counting sort
    for (int i = t; i < CHUNK_C; i += 256) {
        int2 v = stage[i];
        if (v.x >= 0) {
            int b = bidx[i];
            int p = atomicAdd(&lcur[b], 1);
            sorted[p] = v;
            runid[p]  = (unsigned short)b;
        }
    }
    __syncthreads();

    // position-ordered (coalesced) writeout: addr = delta[b] + p
    int total = lhist[511];
    for (int p = t; p < total; p += 256) {
        int b = runid[p];
        epack[delta[b] + p] = sorted[p];
    }
}

// ===========================================================================
// D. GEMM: x = h @ W, fp32 accumulate, bf16 store to ws. (r3-proven, VALU)
// ===========================================================================
__global__ __launch_bounds__(256) void gcn_gemm_bf16(
    const float* __restrict__ A, const float* __restrict__ W,
    unsigned short* __restrict__ xb, int N)
{
    __shared__ float sA[32][64];
    __shared__ float sB[32][128];

    int t  = threadIdx.x;
    int tx = t & 31;
    int ty = t >> 5;
    int r0 = blockIdx.x * 64;

    float4 acc[8];
#pragma unroll
    for (int i = 0; i < 8; ++i) acc[i] = make_float4(0.f, 0.f, 0.f, 0.f);

    for (int kc = 0; kc < 4; ++kc) {
#pragma unroll
        for (int it = 0; it < 2; ++it) {
            int r    = (t >> 3) + it * 32;
            int kk   = (t & 7) * 4;
            int row  = r0 + r;
            int rowc = row < N ? row : N - 1;
            float4 v = *reinterpret_cast<const float4*>(
                A + (size_t)rowc * D + kc * 32 + kk);
            sA[kk + 0][r] = v.x;
            sA[kk + 1][r] = v.y;
            sA[kk + 2][r] = v.z;
            sA[kk + 3][r] = v.w;
        }
#pragma unroll
        for (int it = 0; it < 4; ++it) {
            int g  = t + it * 256;
            int k  = g >> 5;
            int cc = (g & 31) * 4;
            *reinterpret_cast<float4*>(&sB[k][cc]) =
                *reinterpret_cast<const float4*>(W + (size_t)(kc * 32 + k) * D + cc);
        }
        __syncthreads();

#pragma unroll
        for (int kk = 0; kk < 32; ++kk) {
            float4 bv = *reinterpret_cast<const float4*>(&sB[kk][tx * 4]);
#pragma unroll
            for (int i = 0; i < 8; ++i) {
                float a = sA[kk][ty * 8 + i];
                acc[i].x += a * bv.x;
                acc[i].y += a * bv.y;
                acc[i].z += a * bv.z;
                acc[i].w += a * bv.w;
            }
        }
        __syncthreads();
    }

#pragma unroll
    for (int i = 0; i < 8; ++i) {
        int row = r0 + ty * 8 + i;
        if (row < N) {
            ushort4 q;
            q.x = f2bf(acc[i].x);
            q.y = f2bf(acc[i].y);
            q.z = f2bf(acc[i].z);
            q.w = f2bf(acc[i].w);
            *reinterpret_cast<ushort4*>(xb + (size_t)row * D + tx * 4) = q;
        }
    }
}

// ===========================================================================
// E. fused filter + LDS counting-sort + gather + epilogue.
//    Block b2 owns nodes [b2*128, b2*128+128) = half of coarse bucket b2>>1.
// ===========================================================================
__global__ __launch_bounds__(256) void fused_gather(
    const unsigned short* __restrict__ xb, const int* __restrict__ cstart,
    const int2* __restrict__ epack, const float* __restrict__ bias,
    float* __restrict__ out, int N)
{
    __shared__ int2 sorted[CAPD];
    __shared__ int lcnt[GNODES];
    __shared__ int lbase[GNODES + 1];
    __shared__ int lcur[GNODES];

    int t    = threadIdx.x;
    int b2   = blockIdx.x;
    int cb   = b2 >> 1;
    int half = b2 & 1;
    int n0   = b2 * GNODES;

    int rbeg = cstart[cb];
    int rend = cstart[cb + 1];

    if (t < GNODES) lcnt[t] = 0;
    __syncthreads();

    // Phase A: per-node counts (filter this half of the bucket)
    for (int i = rbeg + t; i < rend; i += 256) {
        int pk = epack[i].x;
        int dl = (pk >> SRCBITS) & (CNODES - 1);
        if ((dl >> 7) == half) atomicAdd(&lcnt[dl & (GNODES - 1)], 1);
    }
    __syncthreads();

    // Phase B: inclusive scan over 128
    for (int off = 1; off < GNODES; off <<= 1) {
        int v = (t < GNODES && t >= off) ? lcnt[t - off] : 0;
        __syncthreads();
        if (t < GNODES) lcnt[t] += v;
        __syncthreads();
    }
    if (t == 0) lbase[0] = 0;
    if (t < GNODES) lbase[t + 1] = lcnt[t];
    __syncthreads();
    if (t < GNODES) lcur[t] = lbase[t];
    int total = lbase[GNODES];
    __syncthreads();

    int g = t >> 5, lane = t & 31, c = lane << 2;
    float4 bb = *reinterpret_cast<const float4*>(bias + c);

    if (total <= CAPD) {
        // Phase C: LDS counting sort by node
        for (int i = rbeg + t; i < rend; i += 256) {
            int2 v = epack[i];
            int dl = (v.x >> SRCBITS) & (CNODES - 1);
            if ((dl >> 7) == half) {
                int p = atomicAdd(&lcur[dl & (GNODES - 1)], 1);
                sorted[p] = make_int2(v.x & SRCMASK, v.y);
            }
        }
        __syncthreads();

        // Phase D: gather (8 node-groups x 32 lanes, ushort4 per lane)
        for (int nd = g; nd < GNODES; nd += 8) {
            int node = n0 + nd;
            if (node >= N) continue;
            int jb = lbase[nd], je = lbase[nd + 1];
            float4 acc = make_float4(0.f, 0.f, 0.f, 0.f);
            int j = jb;
            for (; j + 3 < je; j += 4) {
                int2 e0 = sorted[j], e1 = sorted[j + 1];
                int2 e2 = sorted[j + 2], e3 = sorted[j + 3];
                ushort4 q0 = *reinterpret_cast<const ushort4*>(xb + (size_t)e0.x * D + c);
                ushort4 q1 = *reinterpret_cast<const ushort4*>(xb + (size_t)e1.x * D + c);
                ushort4 q2 = *reinterpret_cast<const ushort4*>(xb + (size_t)e2.x * D + c);
                ushort4 q3 = *reinterpret_cast<const ushort4*>(xb + (size_t)e3.x * D + c);
                float w0 = __int_as_float(e0.y), w1 = __int_as_float(e1.y);
                float w2 = __int_as_float(e2.y), w3 = __int_as_float(e3.y);
                acc.x += w0 * bf2f(q0.x) + w1 * bf2f(q1.x) + w2 * bf2f(q2.x) + w3 * bf2f(q3.x);
                acc.y += w0 * bf2f(q0.y) + w1 * bf2f(q1.y) + w2 * bf2f(q2.y) + w3 * bf2f(q3.y);
                acc.z += w0 * bf2f(q0.z) + w1 * bf2f(q1.z) + w2 * bf2f(q2.z) + w3 * bf2f(q3.z);
                acc.w += w0 * bf2f(q0.w) + w1 * bf2f(q1.w) + w2 * bf2f(q2.w) + w3 * bf2f(q3.w);
            }
            for (; j < je; ++j) {
                int2 e0 = sorted[j];
                ushort4 q0 = *reinterpret_cast<const ushort4*>(xb + (size_t)e0.x * D + c);
                float w0 = __int_as_float(e0.y);
                acc.x += w0 * bf2f(q0.x);
                acc.y += w0 * bf2f(q0.y);
                acc.z += w0 * bf2f(q0.z);
                acc.w += w0 * bf2f(q0.w);
            }
            float4 v;
            v.x = fmaxf(acc.x + bb.x, 0.f);
            v.y = fmaxf(acc.y + bb.y, 0.f);
            v.z = fmaxf(acc.z + bb.z, 0.f);
            v.w = fmaxf(acc.w + bb.w, 0.f);
            *reinterpret_cast<float4*>(out + (size_t)node * D + c) = v;
        }
    } else {
        // slow-but-correct fallback (never triggers for this input):
        // each node-group scans the whole region filtering its node.
        for (int nd = g; nd < GNODES; nd += 8) {
            int node = n0 + nd;
            if (node >= N) continue;
            int dlt = half * GNODES + nd;
            float4 acc = make_float4(0.f, 0.f, 0.f, 0.f);
            for (int i = rbeg; i < rend; ++i) {
                int2 v = epack[i];
                if (((v.x >> SRCBITS) & (CNODES - 1)) == dlt) {
                    ushort4 q = *reinterpret_cast<const ushort4*>(
                        xb + (size_t)(v.x & SRCMASK) * D + c);
                    float w = __int_as_float(v.y);
                    acc.x += w * bf2f(q.x);
                    acc.y += w * bf2f(q.y);
                    acc.z += w * bf2f(q.z);
                    acc.w += w * bf2f(q.w);
                }
            }
            float4 v;
            v.x = fmaxf(acc.x + bb.x, 0.f);
            v.y = fmaxf(acc.y + bb.y, 0.f);
            v.z = fmaxf(acc.z + bb.z, 0.f);
            v.w = fmaxf(acc.w + bb.w, 0.f);
            *reinterpret_cast<float4*>(out + (size_t)node * D + c) = v;
        }
    }
}

// ===========================================================================
// Fallback path (ws too small): atomic scatter + in-place fp32 GEMM+epilogue
// ===========================================================================
__global__ __launch_bounds__(256) void gcn_scatter(
    const float* __restrict__ h, const int* __restrict__ esrc,
    const int* __restrict__ edst, const float* __restrict__ ew,
    float* __restrict__ agg, int nE)
{
    long long tid = (long long)blockIdx.x * 256 + threadIdx.x;
    int e = (int)(tid >> 5);
    if (e >= nE) return;
    int c = ((int)tid & 31) << 2;
    int s = esrc[e];
    int d = edst[e];
    float w = ew[e];
    const float4 hv = *reinterpret_cast<const float4*>(h + (size_t)s * D + c);
    float* o = agg + (size_t)d * D + c;
    atomicAdd(o + 0, hv.x * w);
    atomicAdd(o + 1, hv.y * w);
    atomicAdd(o + 2, hv.z * w);
    atomicAdd(o + 3, hv.w * w);
}

__global__ __launch_bounds__(256) void gcn_gemm_bias_relu(
    const float* __restrict__ A, const float* __restrict__ W,
    const float* __restrict__ bias, float* __restrict__ out, int N)
{
    __shared__ float sA[32][64];
    __shared__ float sB[32][128];
    int t  = threadIdx.x;
    int tx = t & 31;
    int ty = t >> 5;
    int r0 = blockIdx.x * 64;
    float4 acc[8];
#pragma unroll
    for (int i = 0; i < 8; ++i) acc[i] = make_float4(0.f, 0.f, 0.f, 0.f);
    for (int kc = 0; kc < 4; ++kc) {
#pragma unroll
        for (int it = 0; it < 2; ++it) {
            int r    = (t >> 3) + it * 32;
            int kk   = (t & 7) * 4;
            int row  = r0 + r;
            int rowc = row < N ? row : N - 1;
            float4 v = *reinterpret_cast<const float4*>(
                A + (size_t)rowc * D + kc * 32 + kk);
            sA[kk + 0][r] = v.x;
            sA[kk + 1][r] = v.y;
            sA[kk + 2][r] = v.z;
            sA[kk + 3][r] = v.w;
        }
#pragma unroll
        for (int it = 0; it < 4; ++it) {
            int g  = t + it * 256;
            int k  = g >> 5;
            int cc = (g & 31) * 4;
            *reinterpret_cast<float4*>(&sB[k][cc]) =
                *reinterpret_cast<const float4*>(W + (size_t)(kc * 32 + k) * D + cc);
        }
        __syncthreads();
#pragma unroll
        for (int kk = 0; kk < 32; ++kk) {
            float4 bv = *reinterpret_cast<const float4*>(&sB[kk][tx * 4]);
#pragma unroll
            for (int i = 0; i < 8; ++i) {
                float a = sA[kk][ty * 8 + i];
                acc[i].x += a * bv.x;
                acc[i].y += a * bv.y;
                acc[i].z += a * bv.z;
                acc[i].w += a * bv.w;
            }
        }
        __syncthreads();
    }
    float4 bb = *reinterpret_cast<const float4*>(bias + tx * 4);
#pragma unroll
    for (int i = 0; i < 8; ++i) {
        int row = r0 + ty * 8 + i;
        if (row < N) {
            float4 v;
            v.x = fmaxf(acc[i].x + bb.x, 0.f);
            v.y = fmaxf(acc[i].y + bb.y, 0.f);
            v.z = fmaxf(acc[i].z + bb.z, 0.f);
            v.w = fmaxf(acc[i].w + bb.w, 0.f);
            *reinterpret_cast<float4*>(out + (size_t)row * D + tx * 4) = v;
        }
    }
}

// ---------------------------------------------------------------------------
extern "C" void kernel_launch(void* const* d_in, const int* in_sizes, int n_in,
                              void* d_out, int out_size, void* d_ws, size_t ws_size,
                              hipStream_t stream)
{
    const float* h    = (const float*)d_in[0];
    const int*   esrc = (const int*)  d_in[1];
    const int*   edst = (const int*)  d_in[2];
    const float* ew   = (const float*)d_in[3];
    const float* W    = (const float*)d_in[4];
    const float* bias = (const float*)d_in[5];
    float* out = (float*)d_out;

    const int nE = in_sizes[1];
    const int N  = in_sizes[0] / D;
    const int NB = (N + CNODES - 1) / CNODES;     // coarse buckets

    // ws layout: ccount[NB] | cstart[NB+1] | ccur[NB] | epack[E] int2 | xb[N*D] bf16
    char* base = (char*)d_ws;
    size_t intBytes = ((size_t)NB + (NB + 1) + NB) * 4;
    size_t o1 = (intBytes + 15) & ~(size_t)15;
    size_t o2 = (o1 + (size_t)nE * 8 + 15) & ~(size_t)15;
    size_t need = o2 + (size_t)N * D * 2;

    if (ws_size >= need && NB <= 512) {
        int*  ccount = (int*)base;
        int*  cstart = ccount + NB;
        int*  ccur   = cstart + (NB + 1);
        int2* epack  = (int2*)(base + o1);
        unsigned short* xb = (unsigned short*)(base + o2);

        hipMemsetAsync(ccount, 0, (size_t)NB * sizeof(int), stream);

        int aBlocks = (nE + CHUNK_A - 1) / CHUNK_A;
        coarse_hist<<<aBlocks, 256, 0, stream>>>(edst, ccount, nE, NB);
        coarse_scan<<<1, 512, 0, stream>>>(ccount, cstart, ccur, NB, nE);

        int cBlocks = (nE + CHUNK_C - 1) / CHUNK_C;
        bucket_scatter<<<cBlocks, 256, 0, stream>>>(esrc, edst, ew, ccur, epack, nE);

        int gemmBlocks = (N + 63) / 64;
        gcn_gemm_bf16<<<gemmBlocks, 256, 0, stream>>>(h, W, xb, N);

        int gBlocks = (N + GNODES - 1) / GNODES;
        fused_gather<<<gBlocks, 256, 0, stream>>>(xb, cstart, epack, bias, out, N);
    } else {
        hipMemsetAsync(d_out, 0, (size_t)out_size * sizeof(float), stream);
        long long scatterThreads = (long long)nE * 32;
        int scatterBlocks = (int)((scatterThreads + 255) / 256);
        gcn_scatter<<<scatterBlocks, 256, 0, stream>>>(h, esrc, edst, ew, out, nE);
        int gemmBlocks = (N + 63) / 64;
        gcn_gemm_bias_relu<<<gemmBlocks, 256, 0, stream>>>(out, W, bias, out, N);
    }
}